// Round 1
// baseline (3220.424 us; speedup 1.0000x reference)
//
#include <hip/hip_runtime.h>
#include <math.h>

// LSTM persistent kernel: one block per batch element, 512 threads.
// Thread (base=tid>>2, q=tid&3) owns gate rows base+{0,128,256,384},
// k-chunk [32q, 32q+32). Quad DPP allreduce -> lane-local c/h update.
constexpr int Hdim = 128;
constexpr int TMAX = 4096;

template <int CTRL>
__device__ __forceinline__ float quad_swap(float v) {
  int r = __builtin_amdgcn_update_dpp(0, __float_as_int(v), CTRL, 0xF, 0xF, true);
  return __int_as_float(r);
}

__device__ __forceinline__ float fast_sigmoid(float x) {
  return 1.0f / (1.0f + __expf(-x));
}
__device__ __forceinline__ float fast_tanh(float x) {
  // tanh(x) = 1 - 2/(exp(2x)+1); saturates correctly via inf handling
  return 1.0f - 2.0f / (__expf(2.0f * x) + 1.0f);
}

__global__ __launch_bounds__(512, 2) void lstm_persist(
    const float* __restrict__ data, const float* __restrict__ h0,
    const float* __restrict__ c0, const float* __restrict__ W_ih,
    const float* __restrict__ W_hh, const float* __restrict__ b_ih,
    const float* __restrict__ b_hh, const float* __restrict__ W_out,
    const float* __restrict__ b_out, float* __restrict__ out, int T) {
  __shared__ __align__(16) float xs[TMAX];
  // ping-pong x 4 replicas x 132-float stagger (conflict-free quad reads)
  __shared__ __align__(16) float hrep[2][4][132];

  const int b = blockIdx.x;
  const int tid = threadIdx.x;
  const int q = tid & 3;
  const int base = tid >> 2;

  // Stage this batch's input row into LDS (vectorized, coalesced).
  {
    const float4* src = (const float4*)(data + (size_t)b * T);
    float4* dst = (float4*)xs;
    for (int i = tid; i < T / 4; i += 512) dst[i] = src[i];
  }

  // Load recurrent weights into registers: 4 rows x 32 k-elems = 128 VGPRs.
  float w[4][32];
#pragma unroll
  for (int r = 0; r < 4; ++r) {
    const float* wr = W_hh + (size_t)(base + 128 * r) * Hdim + 32 * q;
#pragma unroll
    for (int j = 0; j < 8; ++j) {
      float4 v = ((const float4*)wr)[j];
      w[r][4 * j + 0] = v.x;
      w[r][4 * j + 1] = v.y;
      w[r][4 * j + 2] = v.z;
      w[r][4 * j + 3] = v.w;
    }
  }
  float wih[4], bsum[4];
#pragma unroll
  for (int r = 0; r < 4; ++r) {
    const int row = base + 128 * r;
    wih[r] = W_ih[row];
    bsum[r] = b_ih[row] + b_hh[row];
  }

  float c = c0[(size_t)b * Hdim + base];
  if (q == 0) {
    const float h = h0[(size_t)b * Hdim + base];
    hrep[0][0][base] = h;
    hrep[0][1][base] = h;
    hrep[0][2][base] = h;
    hrep[0][3][base] = h;
  }
  __syncthreads();

  for (int t = 0; t < T; ++t) {
    // Read my 32-float chunk of h from my staggered replica (ds_read_b128 x8).
    const float4* hp = (const float4*)(&hrep[t & 1][q][32 * q]);
    float4 hv[8];
#pragma unroll
    for (int j = 0; j < 8; ++j) hv[j] = hp[j];

    float s0 = 0.f, s1 = 0.f, s2 = 0.f, s3 = 0.f;
#pragma unroll
    for (int j = 0; j < 8; ++j) {
      s0 = fmaf(w[0][4 * j + 0], hv[j].x, s0);
      s0 = fmaf(w[0][4 * j + 1], hv[j].y, s0);
      s0 = fmaf(w[0][4 * j + 2], hv[j].z, s0);
      s0 = fmaf(w[0][4 * j + 3], hv[j].w, s0);
      s1 = fmaf(w[1][4 * j + 0], hv[j].x, s1);
      s1 = fmaf(w[1][4 * j + 1], hv[j].y, s1);
      s1 = fmaf(w[1][4 * j + 2], hv[j].z, s1);
      s1 = fmaf(w[1][4 * j + 3], hv[j].w, s1);
      s2 = fmaf(w[2][4 * j + 0], hv[j].x, s2);
      s2 = fmaf(w[2][4 * j + 1], hv[j].y, s2);
      s2 = fmaf(w[2][4 * j + 2], hv[j].z, s2);
      s2 = fmaf(w[2][4 * j + 3], hv[j].w, s2);
      s3 = fmaf(w[3][4 * j + 0], hv[j].x, s3);
      s3 = fmaf(w[3][4 * j + 1], hv[j].y, s3);
      s3 = fmaf(w[3][4 * j + 2], hv[j].z, s3);
      s3 = fmaf(w[3][4 * j + 3], hv[j].w, s3);
    }

    // Quad allreduce (DPP quad_perm, stays in VALU pipe). All 4 lanes of the
    // quad end with bitwise-identical full dot products for element `base`.
    s0 += quad_swap<0xB1>(s0);
    s0 += quad_swap<0x4E>(s0);
    s1 += quad_swap<0xB1>(s1);
    s1 += quad_swap<0x4E>(s1);
    s2 += quad_swap<0xB1>(s2);
    s2 += quad_swap<0x4E>(s2);
    s3 += quad_swap<0xB1>(s3);
    s3 += quad_swap<0x4E>(s3);

    const float xt = xs[t];
    const float ig = fast_sigmoid(fmaf(xt, wih[0], bsum[0]) + s0);
    const float fg = fast_sigmoid(fmaf(xt, wih[1], bsum[1]) + s1);
    const float gg = fast_tanh(fmaf(xt, wih[2], bsum[2]) + s2);
    const float og = fast_sigmoid(fmaf(xt, wih[3], bsum[3]) + s3);
    c = fmaf(fg, c, ig * gg);
    const float h = og * fast_tanh(c);

    if (q == 0) {
      float* hn = &hrep[(t + 1) & 1][0][0];
      hn[0 * 132 + base] = h;
      hn[1 * 132 + base] = h;
      hn[2 * 132 + base] = h;
      hn[3 * 132 + base] = h;
    }
    __syncthreads();
  }

  // Final linear: out[b] = h_T . W_out + b_out (wave 0 only).
  if (tid < 64) {
    const float* hf = &hrep[T & 1][0][0];
    float sum = hf[tid] * W_out[tid] + hf[tid + 64] * W_out[tid + 64];
#pragma unroll
    for (int off = 32; off > 0; off >>= 1) sum += __shfl_down(sum, off, 64);
    if (tid == 0) out[b] = sum + b_out[0];
  }
}

extern "C" void kernel_launch(void* const* d_in, const int* in_sizes, int n_in,
                              void* d_out, int out_size, void* d_ws,
                              size_t ws_size, hipStream_t stream) {
  const float* data = (const float*)d_in[0];
  const float* h0 = (const float*)d_in[1];
  const float* c0 = (const float*)d_in[2];
  const float* W_ih = (const float*)d_in[3];
  const float* W_hh = (const float*)d_in[4];
  const float* b_ih = (const float*)d_in[5];
  const float* b_hh = (const float*)d_in[6];
  const float* W_out = (const float*)d_in[7];
  const float* b_out = (const float*)d_in[8];
  float* out = (float*)d_out;

  const int B = in_sizes[1] / Hdim;  // 64
  const int T = in_sizes[0] / B;     // 4096

  lstm_persist<<<B, 512, 0, stream>>>(data, h0, c0, W_ih, W_hh, b_ih, b_hh,
                                      W_out, b_out, out, T);
}